// Round 1
// baseline (2598.073 us; speedup 1.0000x reference)
//
#include <hip/hip_runtime.h>
#include <hip/hip_bf16.h>
#include <math.h>

// Problem constants
#define B_   16
#define IC_  32
#define HW_  128
#define NF_  8
#define OC_  64
#define K_   5
#define GRP_ 8
#define COTOT_ (OC_ * GRP_)   // 512

// ---------------------------------------------------------------------------
// Kernel 1: build rotated+mixed weights
// w[co][ic][ky][kx], co = o*GRP + a
//   w = sum_n relaxed[n][a] * rotate(kernel[n][o][ic], theta_a)
// Rotation matches torch affine_grid+grid_sample (align_corners=False, zero pad)
// ---------------------------------------------------------------------------
__global__ void build_w_kernel(const float* __restrict__ kern,
                               const float* __restrict__ relaxed,
                               float* __restrict__ wout) {
    int idx = blockIdx.x * blockDim.x + threadIdx.x;
    const int TOT = COTOT_ * IC_ * K_ * K_;
    if (idx >= TOT) return;
    int e  = idx % (K_ * K_);
    int t  = idx / (K_ * K_);
    int ic = t & (IC_ - 1);
    int co = t >> 5;            // IC_=32
    int a  = co & (GRP_ - 1);
    int o  = co >> 3;           // GRP_=8
    int i  = e / K_;            // row (y)
    int j  = e - i * K_;        // col (x)

    float theta = -6.283185307179586f / (float)GRP_ * (float)a;
    float cth = cosf(theta), sth = sinf(theta);
    float bx = (2.0f * (float)j + 1.0f) / (float)K_ - 1.0f;
    float by = (2.0f * (float)i + 1.0f) / (float)K_ - 1.0f;
    float gx = cth * bx - sth * by;
    float gy = sth * bx + cth * by;
    float ix = ((gx + 1.0f) * (float)K_ - 1.0f) * 0.5f;
    float iy = ((gy + 1.0f) * (float)K_ - 1.0f) * 0.5f;
    float x0 = floorf(ix), y0 = floorf(iy);
    float wx1 = ix - x0, wy1 = iy - y0;
    float wx0 = 1.0f - wx1, wy0 = 1.0f - wy1;

    float xs[2]  = {x0, x0 + 1.0f};
    float ys[2]  = {y0, y0 + 1.0f};
    float wxs[2] = {wx0, wx1};
    float wys[2] = {wy0, wy1};

    float tw[4];
    int   tyc[4], txc[4];
    #pragma unroll
    for (int dy = 0; dy < 2; ++dy) {
        #pragma unroll
        for (int dx = 0; dx < 2; ++dx) {
            float xx = xs[dx], yy = ys[dy];
            bool valid = (xx >= 0.0f) && (xx < (float)K_) &&
                         (yy >= 0.0f) && (yy < (float)K_);
            int tp = dy * 2 + dx;
            tw[tp]  = wys[dy] * wxs[dx] * (valid ? 1.0f : 0.0f);
            txc[tp] = (int)fminf(fmaxf(xx, 0.0f), (float)(K_ - 1));
            tyc[tp] = (int)fminf(fmaxf(yy, 0.0f), (float)(K_ - 1));
        }
    }

    float acc = 0.0f;
    #pragma unroll
    for (int n = 0; n < NF_; ++n) {
        const float* kb = kern + ((size_t)((n * OC_ + o) * IC_ + ic)) * (K_ * K_);
        float v = 0.0f;
        #pragma unroll
        for (int tp = 0; tp < 4; ++tp)
            v += kb[tyc[tp] * K_ + txc[tp]] * tw[tp];
        acc += relaxed[n * GRP_ + a] * v;
    }
    wout[idx] = acc;
}

// ---------------------------------------------------------------------------
// Kernel 2: direct conv + leaky relu
// block: 256 threads; tile = 32x32 spatial x 8 output channels x 1 batch
// per-thread: 4 spatial rows x 8 channels accumulators
// ---------------------------------------------------------------------------
#define PS 37   // patch row stride (floats)

__global__ __launch_bounds__(256) void conv_kernel(
    const float* __restrict__ x,
    const float* __restrict__ wf,
    float* __restrict__ out) {
    __shared__ float patch[36 * PS];
    __shared__ float wlds[25][8];

    int tid = threadIdx.x;
    int tx = tid & 31;
    int ty = tid >> 5;          // 0..7
    int tile = blockIdx.x;      // 0..15 -> 4x4 tiles of 32x32
    int h0 = (tile >> 2) * 32;
    int w0 = (tile & 3) * 32;
    int cg = blockIdx.y;        // channel group: co = cg*8 + c
    int b  = blockIdx.z;

    const float* xb = x + (size_t)b * IC_ * HW_ * HW_;

    float acc[4][8];
    #pragma unroll
    for (int p = 0; p < 4; ++p)
        #pragma unroll
        for (int c = 0; c < 8; ++c) acc[p][c] = 0.0f;

    for (int ic = 0; ic < IC_; ++ic) {
        __syncthreads();
        // stage input patch (36x36, zero-padded at borders)
        const float* xi = xb + (size_t)ic * HW_ * HW_;
        for (int e = tid; e < 36 * 36; e += 256) {
            int r  = e / 36;
            int cc = e - r * 36;
            int gh = h0 - 2 + r;
            int gw = w0 - 2 + cc;
            float v = 0.0f;
            if (gh >= 0 && gh < HW_ && gw >= 0 && gw < HW_)
                v = xi[gh * HW_ + gw];
            patch[r * PS + cc] = v;
        }
        // stage weights, transposed so channel is contiguous
        if (tid < 200) {
            int c = tid & 7;
            int e = tid >> 3;
            wlds[e][c] = wf[((size_t)(cg * 8 + c) * IC_ + ic) * (K_ * K_) + e];
        }
        __syncthreads();

        #pragma unroll
        for (int ky = 0; ky < K_; ++ky) {
            #pragma unroll
            for (int kx = 0; kx < K_; ++kx) {
                float wv[8];
                #pragma unroll
                for (int c = 0; c < 8; ++c) wv[c] = wlds[ky * K_ + kx][c];
                #pragma unroll
                for (int p = 0; p < 4; ++p) {
                    float xv = patch[(ty + p * 8 + ky) * PS + tx + kx];
                    #pragma unroll
                    for (int c = 0; c < 8; ++c)
                        acc[p][c] = fmaf(xv, wv[c], acc[p][c]);
                }
            }
        }
    }

    // epilogue: leaky relu + store (coalesced over tx)
    #pragma unroll
    for (int p = 0; p < 4; ++p) {
        int h = h0 + ty + p * 8;
        #pragma unroll
        for (int c = 0; c < 8; ++c) {
            float v = acc[p][c];
            v = (v >= 0.0f) ? v : 0.01f * v;
            out[((size_t)b * COTOT_ + cg * 8 + c) * (HW_ * HW_) + h * HW_ + w0 + tx] = v;
        }
    }
}

extern "C" void kernel_launch(void* const* d_in, const int* in_sizes, int n_in,
                              void* d_out, int out_size, void* d_ws, size_t ws_size,
                              hipStream_t stream) {
    const float* x       = (const float*)d_in[0];
    const float* kernel  = (const float*)d_in[1];
    const float* relaxed = (const float*)d_in[2];
    float* out = (float*)d_out;
    float* w   = (float*)d_ws;   // COTOT_*IC_*25 floats = 1.6 MB

    const int wtot = COTOT_ * IC_ * K_ * K_;
    build_w_kernel<<<(wtot + 255) / 256, 256, 0, stream>>>(kernel, relaxed, w);

    dim3 grid(16, COTOT_ / 8, B_);
    conv_kernel<<<grid, 256, 0, stream>>>(x, w, out);
}

// Round 2
// 356.643 us; speedup vs baseline: 7.2848x; 7.2848x over previous
//
#include <hip/hip_runtime.h>
#include <hip/hip_bf16.h>
#include <math.h>

// Problem constants
#define B_   16
#define IC_  32
#define HW_  128
#define NF_  8
#define OC_  64
#define K_   5
#define GRP_ 8
#define COTOT_ (OC_ * GRP_)   // 512
#define XTH  132              // padded spatial (128 + 2*2)

typedef short  short8  __attribute__((ext_vector_type(8)));
typedef unsigned short ushort8 __attribute__((ext_vector_type(8)));
typedef float  f32x4   __attribute__((ext_vector_type(4)));

static __device__ inline unsigned short f2bf(float f) {
    unsigned u = __builtin_bit_cast(unsigned, f);
    unsigned r = (u + 0x7FFFu + ((u >> 16) & 1u)) >> 16;
    return (unsigned short)r;
}

// ---------------------------------------------------------------------------
// Kernel 1: x NCHW fp32 -> padded NHWC bf16   xt[b][hp][wp][ic], hp,wp in [0,132)
// ---------------------------------------------------------------------------
__global__ __launch_bounds__(256) void xform_kernel(
    const float* __restrict__ x, unsigned short* __restrict__ xt) {
    int idx = blockIdx.x * blockDim.x + threadIdx.x;
    const int TOT = B_ * XTH * XTH;
    if (idx >= TOT) return;
    int wp = idx % XTH;
    int t  = idx / XTH;
    int hp = t % XTH;
    int b  = t / XTH;

    unsigned short vals[IC_];
    bool interior = (hp >= 2) && (hp < 2 + HW_) && (wp >= 2) && (wp < 2 + HW_);
    if (interior) {
        const float* xb = x + ((size_t)b * IC_) * (HW_ * HW_) + (hp - 2) * HW_ + (wp - 2);
        #pragma unroll
        for (int ic = 0; ic < IC_; ++ic)
            vals[ic] = f2bf(xb[(size_t)ic * (HW_ * HW_)]);
    } else {
        #pragma unroll
        for (int ic = 0; ic < IC_; ++ic) vals[ic] = 0;
    }
    ushort8* dst = (ushort8*)(xt + (size_t)idx * IC_);
    #pragma unroll
    for (int c = 0; c < 4; ++c) {
        ushort8 v;
        #pragma unroll
        for (int j = 0; j < 8; ++j) v[j] = vals[c * 8 + j];
        dst[c] = v;
    }
}

// ---------------------------------------------------------------------------
// Kernel 2: rotated+mixed weights -> bf16, layout wt[ky][kx][co][ic]
// ---------------------------------------------------------------------------
__global__ __launch_bounds__(256) void build_w_kernel(
    const float* __restrict__ kern,
    const float* __restrict__ relaxed,
    unsigned short* __restrict__ wt) {
    int idx = blockIdx.x * blockDim.x + threadIdx.x;
    const int TOT = 25 * COTOT_ * IC_;
    if (idx >= TOT) return;
    int ic = idx & (IC_ - 1);
    int t  = idx >> 5;
    int co = t & (COTOT_ - 1);
    int e  = t >> 9;            // ky*5+kx
    int a  = co & (GRP_ - 1);
    int o  = co >> 3;
    int i  = e / K_;            // ky
    int j  = e - i * K_;        // kx

    float theta = -6.283185307179586f / (float)GRP_ * (float)a;
    float cth = cosf(theta), sth = sinf(theta);
    float bx = (2.0f * (float)j + 1.0f) / (float)K_ - 1.0f;
    float by = (2.0f * (float)i + 1.0f) / (float)K_ - 1.0f;
    float gx = cth * bx - sth * by;
    float gy = sth * bx + cth * by;
    float ix = ((gx + 1.0f) * (float)K_ - 1.0f) * 0.5f;
    float iy = ((gy + 1.0f) * (float)K_ - 1.0f) * 0.5f;
    float x0 = floorf(ix), y0 = floorf(iy);
    float wx1 = ix - x0, wy1 = iy - y0;
    float wx0 = 1.0f - wx1, wy0 = 1.0f - wy1;

    float xs2[2]  = {x0, x0 + 1.0f};
    float ys2[2]  = {y0, y0 + 1.0f};
    float wxs[2] = {wx0, wx1};
    float wys[2] = {wy0, wy1};

    float tw[4];
    int   tyc[4], txc[4];
    #pragma unroll
    for (int dy = 0; dy < 2; ++dy) {
        #pragma unroll
        for (int dx = 0; dx < 2; ++dx) {
            float xx = xs2[dx], yy = ys2[dy];
            bool valid = (xx >= 0.0f) && (xx < (float)K_) &&
                         (yy >= 0.0f) && (yy < (float)K_);
            int tp = dy * 2 + dx;
            tw[tp]  = wys[dy] * wxs[dx] * (valid ? 1.0f : 0.0f);
            txc[tp] = (int)fminf(fmaxf(xx, 0.0f), (float)(K_ - 1));
            tyc[tp] = (int)fminf(fmaxf(yy, 0.0f), (float)(K_ - 1));
        }
    }

    float acc = 0.0f;
    #pragma unroll
    for (int n = 0; n < NF_; ++n) {
        const float* kb = kern + ((size_t)((n * OC_ + o) * IC_ + ic)) * (K_ * K_);
        float v = 0.0f;
        #pragma unroll
        for (int tp = 0; tp < 4; ++tp)
            v += kb[tyc[tp] * K_ + txc[tp]] * tw[tp];
        acc += relaxed[n * GRP_ + a] * v;
    }
    wt[idx] = f2bf(acc);
}

// ---------------------------------------------------------------------------
// Kernel 3: MFMA implicit-GEMM conv + leaky relu
// block = 256 thr (4 waves): 64 co x (2 h-rows x 128 w)
// wave  = 4x4 fragments of 16x16: 64 co x 64 w
// M = co, N = spatial(w), K = ic (32) x 25 shifts
// ---------------------------------------------------------------------------
__global__ __launch_bounds__(256, 2) void conv_mfma_kernel(
    const unsigned short* __restrict__ xt,
    const unsigned short* __restrict__ wt,
    float* __restrict__ out) {
    // x tile: [chunk(4)][row(6)][w(132)][8ic] bf16 = 50688 B
    __shared__ __align__(16) unsigned short xs[4 * 6 * XTH * 8];
    // w tile (one ky): [kx(5)][chunk(4)][co(64)][8ic] bf16 = 20480 B
    __shared__ __align__(16) unsigned short wsh[5 * 4 * 64 * 8];

    int tid  = threadIdx.x;
    int lane = tid & 63;
    int wv   = tid >> 6;          // 0..3
    int l15  = lane & 15;
    int l4   = lane >> 4;         // 0..3 (quarter-wave = ic chunk)

    int cg = blockIdx.x;          // 0..7  -> cobase = cg*64
    int hp = blockIdx.y;          // 0..63 -> output rows 2*hp, 2*hp+1
    int b  = blockIdx.z;
    int cobase = cg * 64;
    int h0 = hp * 2;

    // ---- stage x halo once: padded rows h0..h0+5, full width ----
    {
        const unsigned short* xb = xt + (((size_t)b * XTH + h0) * XTH) * IC_;
        for (int e = tid; e < 4 * 6 * XTH; e += 256) {
            int w  = e % XTH;
            int t2 = e / XTH;
            int r  = t2 % 6;
            int ch = t2 / 6;
            const ushort8* src = (const ushort8*)(xb + ((size_t)r * XTH + w) * IC_ + ch * 8);
            *(ushort8*)&xs[e * 8] = *src;
        }
    }

    f32x4 acc[4][4];
    #pragma unroll
    for (int m = 0; m < 4; ++m)
        #pragma unroll
        for (int n = 0; n < 4; ++n) acc[m][n] = (f32x4)(0.0f);

    int hr = wv >> 1;             // wave's output row (0/1)
    int wb = (wv & 1) * 64;       // wave's w base

    for (int ky = 0; ky < 5; ++ky) {
        __syncthreads();          // covers x staging (ky=0) and wsh reuse
        // ---- stage weights for this ky: [kx][chunk][co][8] ----
        {
            const unsigned short* wbp = wt + ((size_t)(ky * 5) * COTOT_ + cobase) * IC_;
            for (int e = tid; e < 5 * 4 * 64; e += 256) {
                int co = e & 63;
                int ch = (e >> 6) & 3;
                int kx = e >> 8;
                const ushort8* src = (const ushort8*)(wbp + ((size_t)kx * COTOT_ + co) * IC_ + ch * 8);
                *(ushort8*)&wsh[e * 8] = *src;
            }
        }
        __syncthreads();

        #pragma unroll
        for (int kx = 0; kx < 5; ++kx) {
            short8 af[4], bf[4];
            #pragma unroll
            for (int m = 0; m < 4; ++m)
                af[m] = *(const short8*)&wsh[((kx * 4 + l4) * 64 + m * 16 + l15) * 8];
            #pragma unroll
            for (int n = 0; n < 4; ++n)
                bf[n] = *(const short8*)&xs[((l4 * 6 + hr + ky) * XTH + (wb + n * 16 + l15 + kx)) * 8];
            #pragma unroll
            for (int m = 0; m < 4; ++m)
                #pragma unroll
                for (int n = 0; n < 4; ++n)
                    acc[m][n] = __builtin_amdgcn_mfma_f32_16x16x32_bf16(
                        af[m], bf[n], acc[m][n], 0, 0, 0);
        }
    }

    // ---- epilogue: leaky relu + store ----
    int h = h0 + hr;
    #pragma unroll
    for (int m = 0; m < 4; ++m) {
        #pragma unroll
        for (int n = 0; n < 4; ++n) {
            #pragma unroll
            for (int r = 0; r < 4; ++r) {
                int co = cobase + m * 16 + l4 * 4 + r;
                int w  = wb + n * 16 + l15;
                float v = acc[m][n][r];
                v = (v >= 0.0f) ? v : 0.01f * v;
                out[((size_t)b * COTOT_ + co) * (HW_ * HW_) + h * HW_ + w] = v;
            }
        }
    }
}

extern "C" void kernel_launch(void* const* d_in, const int* in_sizes, int n_in,
                              void* d_out, int out_size, void* d_ws, size_t ws_size,
                              hipStream_t stream) {
    const float* x       = (const float*)d_in[0];
    const float* kernel  = (const float*)d_in[1];
    const float* relaxed = (const float*)d_in[2];
    float* out = (float*)d_out;

    unsigned short* xt = (unsigned short*)d_ws;                       // 17,842,176 B
    unsigned short* wt = (unsigned short*)((char*)d_ws + (size_t)B_ * XTH * XTH * IC_ * 2);

    const int xtot = B_ * XTH * XTH;
    xform_kernel<<<(xtot + 255) / 256, 256, 0, stream>>>(x, xt);

    const int wtot = 25 * COTOT_ * IC_;
    build_w_kernel<<<(wtot + 255) / 256, 256, 0, stream>>>(kernel, relaxed, wt);

    dim3 grid(COTOT_ / 64, HW_ / 2, B_);
    conv_mfma_kernel<<<grid, 256, 0, stream>>>(xt, wt, out);
}

// Round 3
// 269.735 us; speedup vs baseline: 9.6319x; 1.3222x over previous
//
#include <hip/hip_runtime.h>
#include <hip/hip_bf16.h>
#include <math.h>

// Problem constants
#define B_   16
#define IC_  32
#define HW_  128
#define NF_  8
#define OC_  64
#define K_   5
#define GRP_ 8
#define COTOT_ (OC_ * GRP_)   // 512
#define XTH  132              // padded spatial (128 + 2*2)

typedef short  short8  __attribute__((ext_vector_type(8)));
typedef unsigned short ushort8 __attribute__((ext_vector_type(8)));
typedef float  f32x4   __attribute__((ext_vector_type(4)));

static __device__ inline unsigned short f2bf(float f) {
    unsigned u = __builtin_bit_cast(unsigned, f);
    unsigned r = (u + 0x7FFFu + ((u >> 16) & 1u)) >> 16;
    return (unsigned short)r;
}

// async global -> LDS, 16 bytes per lane
__device__ __forceinline__ void gload16(void* lds, const void* g) {
    __builtin_amdgcn_global_load_lds(
        (const __attribute__((address_space(1))) unsigned int*)g,
        (__attribute__((address_space(3))) unsigned int*)lds, 16, 0, 0);
}

// ---------------------------------------------------------------------------
// Kernel 1: x NCHW fp32 -> padded NHWC bf16   xt[b][hp][wp][ic]
// ---------------------------------------------------------------------------
__global__ __launch_bounds__(256) void xform_kernel(
    const float* __restrict__ x, unsigned short* __restrict__ xt) {
    int idx = blockIdx.x * blockDim.x + threadIdx.x;
    const int TOT = B_ * XTH * XTH;
    if (idx >= TOT) return;
    int wp = idx % XTH;
    int t  = idx / XTH;
    int hp = t % XTH;
    int b  = t / XTH;

    unsigned short vals[IC_];
    bool interior = (hp >= 2) && (hp < 2 + HW_) && (wp >= 2) && (wp < 2 + HW_);
    if (interior) {
        const float* xb = x + ((size_t)b * IC_) * (HW_ * HW_) + (hp - 2) * HW_ + (wp - 2);
        #pragma unroll
        for (int ic = 0; ic < IC_; ++ic)
            vals[ic] = f2bf(xb[(size_t)ic * (HW_ * HW_)]);
    } else {
        #pragma unroll
        for (int ic = 0; ic < IC_; ++ic) vals[ic] = 0;
    }
    ushort8* dst = (ushort8*)(xt + (size_t)idx * IC_);
    #pragma unroll
    for (int c = 0; c < 4; ++c) {
        ushort8 v;
        #pragma unroll
        for (int j = 0; j < 8; ++j) v[j] = vals[c * 8 + j];
        dst[c] = v;
    }
}

// ---------------------------------------------------------------------------
// Kernel 2: rotated+mixed weights -> bf16, layout wt[tap25][co512][ic32]
// ---------------------------------------------------------------------------
__global__ __launch_bounds__(256) void build_w_kernel(
    const float* __restrict__ kern,
    const float* __restrict__ relaxed,
    unsigned short* __restrict__ wt) {
    int idx = blockIdx.x * blockDim.x + threadIdx.x;
    const int TOT = 25 * COTOT_ * IC_;
    if (idx >= TOT) return;
    int ic = idx & (IC_ - 1);
    int t  = idx >> 5;
    int co = t & (COTOT_ - 1);
    int e  = t >> 9;            // ky*5+kx
    int a  = co & (GRP_ - 1);
    int o  = co >> 3;
    int i  = e / K_;            // ky
    int j  = e - i * K_;        // kx

    float theta = -6.283185307179586f / (float)GRP_ * (float)a;
    float cth = cosf(theta), sth = sinf(theta);
    float bx = (2.0f * (float)j + 1.0f) / (float)K_ - 1.0f;
    float by = (2.0f * (float)i + 1.0f) / (float)K_ - 1.0f;
    float gx = cth * bx - sth * by;
    float gy = sth * bx + cth * by;
    float ix = ((gx + 1.0f) * (float)K_ - 1.0f) * 0.5f;
    float iy = ((gy + 1.0f) * (float)K_ - 1.0f) * 0.5f;
    float x0 = floorf(ix), y0 = floorf(iy);
    float wx1 = ix - x0, wy1 = iy - y0;
    float wx0 = 1.0f - wx1, wy0 = 1.0f - wy1;

    float xs2[2]  = {x0, x0 + 1.0f};
    float ys2[2]  = {y0, y0 + 1.0f};
    float wxs[2] = {wx0, wx1};
    float wys[2] = {wy0, wy1};

    float tw[4];
    int   tyc[4], txc[4];
    #pragma unroll
    for (int dy = 0; dy < 2; ++dy) {
        #pragma unroll
        for (int dx = 0; dx < 2; ++dx) {
            float xx = xs2[dx], yy = ys2[dy];
            bool valid = (xx >= 0.0f) && (xx < (float)K_) &&
                         (yy >= 0.0f) && (yy < (float)K_);
            int tp = dy * 2 + dx;
            tw[tp]  = wys[dy] * wxs[dx] * (valid ? 1.0f : 0.0f);
            txc[tp] = (int)fminf(fmaxf(xx, 0.0f), (float)(K_ - 1));
            tyc[tp] = (int)fminf(fmaxf(yy, 0.0f), (float)(K_ - 1));
        }
    }

    float acc = 0.0f;
    #pragma unroll
    for (int n = 0; n < NF_; ++n) {
        const float* kb = kern + ((size_t)((n * OC_ + o) * IC_ + ic)) * (K_ * K_);
        float v = 0.0f;
        #pragma unroll
        for (int tp = 0; tp < 4; ++tp)
            v += kb[tyc[tp] * K_ + txc[tp]] * tw[tp];
        acc += relaxed[n * GRP_ + a] * v;
    }
    wt[idx] = f2bf(acc);
}

// ---------------------------------------------------------------------------
// Kernel 3: MFMA implicit-GEMM conv + leaky relu
// block = 256 thr (4 waves) = 128 co x 2 h x 128 w
// wave  = 8x4 fragments of 16x16: 128 co x 64 w at one h row
// K = 25 taps x ic32; weights double-buffered per tap via global_load_lds
// ---------------------------------------------------------------------------
__global__ __launch_bounds__(256, 2) void conv_mfma_kernel(
    const unsigned short* __restrict__ xt,
    const unsigned short* __restrict__ wt,
    float* __restrict__ out) {
    // x tile: [chunk4][row6][w132][8ic] bf16 = 50688 B, staged once
    __shared__ __align__(16) unsigned short xs[4 * 6 * XTH * 8];
    // w tap double-buffer: [chunk4][co128][8ic] bf16 = 8192 B each
    __shared__ __align__(16) unsigned short wbuf[2][4 * 128 * 8];

    int tid  = threadIdx.x;
    int lane = tid & 63;
    int wv   = tid >> 6;          // 0..3
    int l15  = lane & 15;
    int l4   = lane >> 4;         // 0..3 (k-chunk)
    int hr   = wv >> 1;           // wave's output row (0/1)
    int wn   = wv & 1;            // wave's w half (0/1)

    int cg = blockIdx.x;          // 0..3 -> cobase = cg*128
    int hp = blockIdx.y;          // 0..63 -> rows 2*hp, 2*hp+1
    int b  = blockIdx.z;
    int cobase = cg * 128;
    int h0 = hp * 2;

    // ---- stage x halo once (async): rows h0..h0+5, full padded width ----
    {
        const unsigned short* xb = xt + (((size_t)b * XTH + h0) * XTH) * IC_;
        for (int i = 0; i < 13; ++i) {
            int s = i * 256 + tid;          // slot: 16B each, 3168 total
            if (s < 3168) {
                int ch  = s / (6 * XTH);
                int rem = s - ch * (6 * XTH);
                int row = rem / XTH;
                int w   = rem - row * XTH;
                gload16(&xs[s * 8], xb + ((size_t)row * XTH + w) * IC_ + ch * 8);
            }
        }
    }
    // ---- stage weights for tap 0 into buf 0 ----
    {
        const unsigned short* wsrc = wt + (size_t)cobase * IC_;
        #pragma unroll
        for (int i = 0; i < 2; ++i) {
            int s  = i * 256 + tid;         // 512 slots of 16B
            int ch = s >> 7;
            int co = s & 127;
            gload16(&wbuf[0][s * 8], wsrc + (size_t)co * IC_ + ch * 8);
        }
    }
    __syncthreads();   // drains vmcnt, all staging visible

    f32x4 acc[8][4];
    #pragma unroll
    for (int m = 0; m < 8; ++m)
        #pragma unroll
        for (int n = 0; n < 4; ++n) acc[m][n] = (f32x4)(0.0f);

    for (int t = 0; t < 25; ++t) {
        int bi = t & 1;
        // ---- issue next tap's weight stage into other buffer ----
        if (t < 24) {
            const unsigned short* wsrc = wt + ((size_t)(t + 1) * COTOT_ + cobase) * IC_;
            #pragma unroll
            for (int i = 0; i < 2; ++i) {
                int s  = i * 256 + tid;
                int ch = s >> 7;
                int co = s & 127;
                gload16(&wbuf[bi ^ 1][s * 8], wsrc + (size_t)co * IC_ + ch * 8);
            }
        }
        // ---- compute current tap ----
        int ky = t / 5;
        int kx = t - ky * 5;
        int row = hr + ky;

        short8 af[8], bf[4];
        #pragma unroll
        for (int m = 0; m < 8; ++m)
            af[m] = *(const short8*)&wbuf[bi][(l4 * 128 + m * 16 + l15) * 8];
        #pragma unroll
        for (int n = 0; n < 4; ++n)
            bf[n] = *(const short8*)&xs[((l4 * 6 + row) * XTH +
                                        (wn * 64 + n * 16 + l15 + kx)) * 8];
        #pragma unroll
        for (int m = 0; m < 8; ++m)
            #pragma unroll
            for (int n = 0; n < 4; ++n)
                acc[m][n] = __builtin_amdgcn_mfma_f32_16x16x32_bf16(
                    af[m], bf[n], acc[m][n], 0, 0, 0);

        __syncthreads();   // implies vmcnt(0): next tap's stage (issued above) done
    }

    // ---- epilogue: leaky relu + store ----
    int h = h0 + hr;
    float* ob = out + ((size_t)b * COTOT_ + cobase) * (HW_ * HW_)
                    + (size_t)h * HW_ + wn * 64;
    #pragma unroll
    for (int m = 0; m < 8; ++m) {
        #pragma unroll
        for (int n = 0; n < 4; ++n) {
            #pragma unroll
            for (int r = 0; r < 4; ++r) {
                int co = m * 16 + l4 * 4 + r;
                int w  = n * 16 + l15;
                float v = acc[m][n][r];
                v = (v >= 0.0f) ? v : 0.01f * v;
                ob[(size_t)co * (HW_ * HW_) + w] = v;
            }
        }
    }
}

extern "C" void kernel_launch(void* const* d_in, const int* in_sizes, int n_in,
                              void* d_out, int out_size, void* d_ws, size_t ws_size,
                              hipStream_t stream) {
    const float* x       = (const float*)d_in[0];
    const float* kernel  = (const float*)d_in[1];
    const float* relaxed = (const float*)d_in[2];
    float* out = (float*)d_out;

    unsigned short* xt = (unsigned short*)d_ws;   // 16*132*132*32*2 = 17,842,176 B
    unsigned short* wt = (unsigned short*)((char*)d_ws + (size_t)B_ * XTH * XTH * IC_ * 2);

    const int xtot = B_ * XTH * XTH;
    xform_kernel<<<(xtot + 255) / 256, 256, 0, stream>>>(x, xt);

    const int wtot = 25 * COTOT_ * IC_;
    build_w_kernel<<<(wtot + 255) / 256, 256, 0, stream>>>(kernel, relaxed, wt);

    dim3 grid(COTOT_ / 128, HW_ / 2, B_);
    conv_mfma_kernel<<<grid, 256, 0, stream>>>(xt, wt, out);
}